// Round 14
// baseline (399.730 us; speedup 1.0000x reference)
//
#include <hip/hip_runtime.h>
#include <math.h>

#define BQ   4096
#define FD   512
#define NATT 8192
#define NDB  (BQ + NATT)   // 12288
#define DD   (2 * FD)      // 1024
#define KTOP 32
#define EPSF 1e-7f

#define QT   32            // 4096/128 query tiles
#define NT   96            // 12288/128 col-tiles per row for g_tmax
// tiles: att region 32x64 = 2048, Q-Q upper triangle incl diag = 528
#define NTILES (2048 + 528)   // 2576 = 8 * 322 -> bijective XCD swizzle

typedef __attribute__((ext_vector_type(8))) short bf16x8;
typedef __attribute__((ext_vector_type(8))) unsigned short u16x8;
typedef __attribute__((ext_vector_type(4))) float f32x4;

// Packed pre-tiled db: [panel(96,128-row)][kchunk(32)][hi|lo(2)][kc(4)][row(128)][8]
__device__ unsigned short g_pk[(size_t)NDB * DD * 2];  // 48 MB
__device__ float g_sims[(size_t)BQ * NDB];             // 201 MB
__device__ float g_tmax[(size_t)BQ * NT];              // 4.5 MB per-(row,128-tile) maxima

__device__ __forceinline__ unsigned fkey(unsigned u) {
    return u ^ (unsigned)(((int)u >> 31) | 0x80000000);  // monotonic float->uint
}
__device__ __forceinline__ unsigned short f2bf(float f) {   // RNE f32->bf16
    unsigned u = __float_as_uint(f);
    return (unsigned short)((u + 0x7FFFu + ((u >> 16) & 1u)) >> 16);
}
__device__ __forceinline__ float bf2f(unsigned short h) {
    return __uint_as_float((unsigned)h << 16);
}
__device__ __forceinline__ float frsq(float x) {
#if __has_builtin(__builtin_amdgcn_rsqf)
    return __builtin_amdgcn_rsqf(x);
#else
    return rsqrtf(x);
#endif
}
__device__ __forceinline__ void gld16(const void* g, void* l) {
    __builtin_amdgcn_global_load_lds(
        (const __attribute__((address_space(1))) void*)g,
        (__attribute__((address_space(3))) void*)l, 16, 0, 0);
}

// ---------------- 1. L2-normalize db rows, emit packed bf16 hi/lo ------------
// Block = 16 consecutive rows. Thread (r=t>>4, l16=t&15) owns 32 re + 32 im
// elements of row r.  Stores are ushort8 (16B); the 4 rows of a wave write
// adjacent 16B chunks per (kchunk,hl,kc) -> coalesced 64B transactions.
__global__ __launch_bounds__(256) void normalize_kernel(
        const float* __restrict__ x_real, const float* __restrict__ x_imag,
        const float* __restrict__ att_real, const float* __restrict__ att_imag) {
    int t = threadIdx.x;
    int r = t >> 4;             // 0..15 row within block (4 per wave)
    int l16 = t & 15;           // 16 threads per row
    int row = blockIdx.x * 16 + r;
    const float *re, *im;
    if (row < BQ) { re = x_real + (size_t)row * FD;          im = x_imag + (size_t)row * FD; }
    else          { re = att_real + (size_t)(row - BQ) * FD; im = att_imag + (size_t)(row - BQ) * FD; }

    float4 vre[8], vim[8];
    float ss = 0.0f;
#pragma unroll
    for (int i = 0; i < 8; ++i) {
        vre[i] = *(const float4*)(re + l16 * 32 + i * 4);
        vim[i] = *(const float4*)(im + l16 * 32 + i * 4);
        ss += vre[i].x * vre[i].x + vre[i].y * vre[i].y + vre[i].z * vre[i].z + vre[i].w * vre[i].w;
        ss += vim[i].x * vim[i].x + vim[i].y * vim[i].y + vim[i].z * vim[i].z + vim[i].w * vim[i].w;
    }
#pragma unroll
    for (int o = 1; o < 16; o <<= 1) ss += __shfl_xor(ss, o);   // 16-lane row reduce
    float ninv = frsq(ss);   // 1/||v||

    // emit 32 els (one kchunk) of hi/lo into the pk layout
    auto emit = [&](const float4* v, int kchunk) {
        unsigned short hi[32], lo[32];
#pragma unroll
        for (int i = 0; i < 8; ++i) {
            float vals[4] = {v[i].x, v[i].y, v[i].z, v[i].w};
#pragma unroll
            for (int j = 0; j < 4; ++j) {
                float nv = vals[j] * ninv;
                unsigned short h = f2bf(nv);
                hi[i * 4 + j] = h;
                lo[i * 4 + j] = f2bf(nv - bf2f(h));
            }
        }
        size_t cb = ((size_t)((row >> 7) * 32 + kchunk) * 2) * 4096 + (size_t)(row & 127) * 8;
#pragma unroll
        for (int kc = 0; kc < 4; ++kc) {
            *(u16x8*)(g_pk + cb + kc * 1024)        = *(u16x8*)&hi[kc * 8];   // hl=0
            *(u16x8*)(g_pk + cb + 4096 + kc * 1024) = *(u16x8*)&lo[kc * 8];   // hl=1
        }
    };
    emit(vre, l16);         // re part: k in [l16*32, l16*32+32)  -> kchunk l16
    emit(vim, 16 + l16);    // im part: k in [512+l16*32, ...)    -> kchunk 16+l16
}

// ---------------- 2. sims via bf16x3 MFMA + per-(row,tile) maxima ------------
// 128x128 tile, BK=32, 4 waves x (4x4) 16x16x32 fragments.  Q-Q region is
// symmetric: upper triangle computed, transpose written from the accumulator.
// XCD-aware bijective swizzle (2576 = 8*322) gives each XCD a contiguous run
// of A-panels for L2 locality.  Epilogue emits per-(row,128-tile) maxima.
__global__ __launch_bounds__(256) void gemm_mfma() {
    __shared__ unsigned short smem[4 * 4096];
    const int t = threadIdx.x;
    const int lane = t & 63, wid = t >> 6;
    const int wr = wid >> 1, wc = wid & 1;
    const int kc = lane >> 4, fr = lane & 15;

    // XCD swizzle, then unrank tile id -> (bm, bn), mirror flag
    int bid = blockIdx.x;
    int tid = (bid & 7) * (NTILES / 8) + (bid >> 3);
    int bm, bn; bool mirror = false;
    if (tid < 2048) { bm = tid >> 6; bn = QT + (tid & 63); }
    else {
        int t2 = tid - 2048;      // upper-triangle rank (row-major, incl diag)
        int r = 0, off = 0;
        while (t2 >= off + (QT - r)) { off += QT - r; ++r; }   // <=32 iters, uniform
        bm = r; bn = r + (t2 - off);
        mirror = (bn != bm);
    }

    f32x4 acc[4][4];
#pragma unroll
    for (int m = 0; m < 4; ++m)
#pragma unroll
        for (int n = 0; n < 4; ++n) acc[m][n] = (f32x4){0.f, 0.f, 0.f, 0.f};

    for (int c = 0; c < 32; ++c) {   // k0 = 32*c
        const unsigned short* apk = g_pk + ((size_t)(bm * 32 + c)) * 8192;
        const unsigned short* bpk = g_pk + ((size_t)(bn * 32 + c)) * 8192;
#pragma unroll
        for (int i = 0; i < 4; ++i) {
            int s = t + i * 256;                       // 0..1023 16B slots
            gld16(apk + (size_t)s * 8, &smem[s * 8]);
            gld16(bpk + (size_t)s * 8, &smem[8192 + s * 8]);
        }
        __syncthreads();

        bf16x8 ah[4], al[4], bh[4], bl[4];
#pragma unroll
        for (int m = 0; m < 4; ++m) {
            int ra = wr * 64 + m * 16 + fr;
            ah[m] = *(const bf16x8*)&smem[(kc * 128 + ra) * 8];
            al[m] = *(const bf16x8*)&smem[4096 + (kc * 128 + ra) * 8];
            int rb = wc * 64 + m * 16 + fr;
            bh[m] = *(const bf16x8*)&smem[8192 + (kc * 128 + rb) * 8];
            bl[m] = *(const bf16x8*)&smem[12288 + (kc * 128 + rb) * 8];
        }
#pragma unroll
        for (int m = 0; m < 4; ++m)
#pragma unroll
            for (int n = 0; n < 4; ++n) {
                acc[m][n] = __builtin_amdgcn_mfma_f32_16x16x32_bf16(ah[m], bh[n], acc[m][n], 0, 0, 0);
                acc[m][n] = __builtin_amdgcn_mfma_f32_16x16x32_bf16(ah[m], bl[n], acc[m][n], 0, 0, 0);
                acc[m][n] = __builtin_amdgcn_mfma_f32_16x16x32_bf16(al[m], bh[n], acc[m][n], 0, 0, 0);
            }
        __syncthreads();
    }
    // normal epilogue: C/D layout col=lane&15, row=(lane>>4)*4+j
    const int crow0 = bm * 128 + wr * 64 + kc * 4;
    const int ccol0 = bn * 128 + wc * 64 + fr;
#pragma unroll
    for (int m = 0; m < 4; ++m)
#pragma unroll
        for (int n = 0; n < 4; ++n)
#pragma unroll
            for (int j = 0; j < 4; ++j)
                g_sims[(size_t)(crow0 + m * 16 + j) * NDB + ccol0 + n * 16] = acc[m][n][j];

    if (mirror) {
        // transposed tile: per lane & frag 4 consecutive cols (j) -> one float4
#pragma unroll
        for (int m = 0; m < 4; ++m)
#pragma unroll
            for (int n = 0; n < 4; ++n) {
                size_t r = (size_t)(bn * 128 + wc * 64 + n * 16 + fr);
                size_t cix = (size_t)(bm * 128 + wr * 64 + m * 16 + kc * 4);
                *(f32x4*)&g_sims[r * NDB + cix] = acc[m][n];
            }
    }

    // --- per-row (and per-col if mirrored) tile maxima for topk threshold ---
    float* rowhalf = (float*)smem;          // [128][2]
    float* colhalf = (float*)smem + 256;    // [128][2]
#pragma unroll
    for (int m = 0; m < 4; ++m)
#pragma unroll
        for (int j = 0; j < 4; ++j) {
            float v = fmaxf(fmaxf(acc[m][0][j], acc[m][1][j]),
                            fmaxf(acc[m][2][j], acc[m][3][j]));
#pragma unroll
            for (int o = 1; o < 16; o <<= 1) v = fmaxf(v, __shfl_xor(v, o));
            if (fr == 0) rowhalf[(wr * 64 + m * 16 + kc * 4 + j) * 2 + wc] = v;
        }
    if (mirror) {
#pragma unroll
        for (int n = 0; n < 4; ++n) {
            float v = acc[0][n][0];
#pragma unroll
            for (int m = 0; m < 4; ++m)
#pragma unroll
                for (int j = 0; j < 4; ++j) v = fmaxf(v, acc[m][n][j]);
            v = fmaxf(v, __shfl_xor(v, 16));
            v = fmaxf(v, __shfl_xor(v, 32));
            if (kc == 0) colhalf[(wc * 64 + n * 16 + fr) * 2 + wr] = v;
        }
    }
    __syncthreads();
    if (t < 128) {
        g_tmax[(size_t)(bm * 128 + t) * NT + bn] = fmaxf(rowhalf[t * 2], rowhalf[t * 2 + 1]);
        if (mirror)
            g_tmax[(size_t)(bn * 128 + t) * NT + bm] = fmaxf(colhalf[t * 2], colhalf[t * 2 + 1]);
    }
}

// ------- 3+4 fused: parallel-rank T + tile-skipping collect + agg ------------
// T = 32nd-largest of the row's 96 tile maxima (parallel rank).  Tiles with
// tmax < T cannot contain a candidate -> stream only qualifying tiles
// (~35-50 of 96, 512B contiguous each).  Candidates -> 64-lane bitonic sort
// (exact numpy tie semantics); exact fallbacks beyond 64/512.
__global__ __launch_bounds__(256) void topk_agg_kernel(
        const float* __restrict__ x_real, const float* __restrict__ x_imag,
        const float* __restrict__ att_real, const float* __restrict__ att_imag,
        const float* __restrict__ alpha_p, float* __restrict__ out) {
    __shared__ float stm[96];
    __shared__ unsigned char tlist[96];
    __shared__ unsigned long long cand[512];
    __shared__ int s_idx[KTOP];
    __shared__ unsigned s_cnt;
    __shared__ int s_ntile;
    __shared__ float s_T;
    __shared__ unsigned long long s_red[4];
    __shared__ unsigned long long s_last;
    int b = blockIdx.x, t = threadIdx.x;
    int wave = t >> 6, lane = t & 63;

    if (t < 96) stm[t] = g_tmax[(size_t)b * NT + t];
    if (t == 0) { s_cnt = 0; s_ntile = 0; }
    __syncthreads();

    // parallel rank: thread t's value has rank #{i: v_i>v || (v_i==v && i<t)}
    if (t < 96) {
        float v = stm[t];
        int cnt = 0;
        for (int i = 0; i < 96; ++i) {
            float o = stm[i];
            cnt += (o > v) || (o == v && i < t);
        }
        if (cnt == KTOP - 1) s_T = v;   // exactly one thread has rank 31
    }
    __syncthreads();
    const float T = s_T;

    // qualifying tile list (tmax >= T); >= 32 entries by construction
    if (t < 96 && stm[t] >= T) {
        int p = atomicAdd(&s_ntile, 1);
        tlist[p] = (unsigned char)t;
    }
    __syncthreads();
    const int ntile = s_ntile;

    // stream only qualifying tiles: 8 tiles/iter, 32 lanes x float4 per tile
    const float* rowp = g_sims + (size_t)b * NDB;
    for (int base = 0; base < ntile; base += 8) {
        int ti = base + (t >> 5);
        if (ti < ntile) {
            int tile = tlist[ti];
            int c4 = (t & 31) * 4;
            float4 v = *(const float4*)(rowp + tile * 128 + c4);
            int gidx = tile * 128 + c4;
            if (v.x >= T) { unsigned p = atomicAdd(&s_cnt, 1u); if (p < 512) cand[p] = ((unsigned long long)fkey(__float_as_uint(v.x)) << 32) | (unsigned)(~(gidx + 0)); }
            if (v.y >= T) { unsigned p = atomicAdd(&s_cnt, 1u); if (p < 512) cand[p] = ((unsigned long long)fkey(__float_as_uint(v.y)) << 32) | (unsigned)(~(gidx + 1)); }
            if (v.z >= T) { unsigned p = atomicAdd(&s_cnt, 1u); if (p < 512) cand[p] = ((unsigned long long)fkey(__float_as_uint(v.z)) << 32) | (unsigned)(~(gidx + 2)); }
            if (v.w >= T) { unsigned p = atomicAdd(&s_cnt, 1u); if (p < 512) cand[p] = ((unsigned long long)fkey(__float_as_uint(v.w)) << 32) | (unsigned)(~(gidx + 3)); }
        }
    }
    __syncthreads();

    int c = (int)s_cnt;
    if (c <= 64) {
        if (wave == 0) {
            unsigned long long vv = (lane < c) ? cand[lane] : 0ull;
#pragma unroll
            for (int k = 2; k <= 64; k <<= 1)
#pragma unroll
                for (int j = k >> 1; j > 0; j >>= 1) {
                    unsigned long long o = __shfl_xor(vv, j);
                    bool lower = (lane & j) == 0;
                    bool desc  = (lane & k) == 0;
                    bool keepmax = (lower == desc);
                    vv = keepmax ? (vv > o ? vv : o) : (vv < o ? vv : o);
                }
            if (lane < KTOP) s_idx[lane] = (int)(~(unsigned)vv);
        }
    } else if (c <= 512) {
        if (wave == 0) {   // serial extraction over <=512 cands
            for (int it = 0; it < KTOP; ++it) {
                unsigned long long m = 0;
                for (int i = lane; i < c; i += 64) m = cand[i] > m ? cand[i] : m;
#pragma unroll
                for (int o = 32; o > 0; o >>= 1) {
                    unsigned long long x = __shfl_xor(m, o);
                    m = x > m ? x : m;
                }
                if (lane == 0) s_idx[it] = (int)(~(unsigned)m);
                for (int i = lane; i < c; i += 64) if (cand[i] == m) cand[i] = 0;
            }
        }
    } else {
        // never expected: exact 32x re-stream extraction over the full row
        const float4* row4 = (const float4*)rowp;
        unsigned long long last = ~0ull;
        for (int it = 0; it < KTOP; ++it) {
            unsigned long long m = 0;
            for (int i = 0; i < 12; ++i) {
                float4 v = row4[t + i * 256];
                int base = 4 * (t + i * 256);
                unsigned long long k;
                k = ((unsigned long long)fkey(__float_as_uint(v.x)) << 32) | (unsigned)(~(base + 0)); if (k < last && k > m) m = k;
                k = ((unsigned long long)fkey(__float_as_uint(v.y)) << 32) | (unsigned)(~(base + 1)); if (k < last && k > m) m = k;
                k = ((unsigned long long)fkey(__float_as_uint(v.z)) << 32) | (unsigned)(~(base + 2)); if (k < last && k > m) m = k;
                k = ((unsigned long long)fkey(__float_as_uint(v.w)) << 32) | (unsigned)(~(base + 3)); if (k < last && k > m) m = k;
            }
#pragma unroll
            for (int o = 32; o > 0; o >>= 1) {
                unsigned long long x = __shfl_xor(m, o);
                m = x > m ? x : m;
            }
            if (lane == 0) s_red[wave] = m;
            __syncthreads();
            if (t == 0) {
                unsigned long long w = s_red[0];
#pragma unroll
                for (int i = 1; i < 4; ++i) w = s_red[i] > w ? s_red[i] : w;
                s_idx[it] = (int)(~(unsigned)w);
                s_last = w;
            }
            __syncthreads();
            last = s_last;
        }
    }
    __syncthreads();

    // ---- aggregation: circular mean over the 32 neighbors + blend ----
    float a = alpha_p[0];
    a = fminf(fmaxf(a, 0.0f), 1.0f);
    int f = 2 * t;
    float sr0 = 0, sc0 = 0, ss0 = 0, sr1 = 0, sc1 = 0, ss1 = 0;
    for (int k = 0; k < KTOP; ++k) {
        int idx = s_idx[k];
        const float *re, *im;
        if (idx < BQ) { re = x_real + (size_t)idx * FD;          im = x_imag + (size_t)idx * FD; }
        else          { re = att_real + (size_t)(idx - BQ) * FD; im = att_imag + (size_t)(idx - BQ) * FD; }
        float2 vr = *(const float2*)(re + f);
        float2 vi = *(const float2*)(im + f);
        float s0 = vr.x * vr.x + vi.x * vi.x;
        if (s0 > 0.0f) {
            float iv = frsq(s0);
            sr0 += s0 * iv; sc0 += vr.x * iv; ss0 += vi.x * iv;
        } else sc0 += 1.0f;                     // atan2(0,0)=0
        float s1 = vr.y * vr.y + vi.y * vi.y;
        if (s1 > 0.0f) {
            float iv = frsq(s1);
            sr1 += s1 * iv; sc1 += vr.y * iv; ss1 += vi.y * iv;
        } else sc1 += 1.0f;
    }
    const float inv = 1.0f / KTOP;
    float mr0 = sr0 * inv + EPSF, mc0 = sc0 * inv, ms0 = ss0 * inv;
    float mr1 = sr1 * inv + EPSF, mc1 = sc1 * inv, ms1 = ss1 * inv;
    float q0 = mc0 * mc0 + ms0 * ms0;
    float q1 = mc1 * mc1 + ms1 * ms1;
    float i0 = (q0 > 0.0f) ? frsq(q0) : 0.0f;   // q==0 -> phi=0 -> cos=1,sin=0
    float i1 = (q1 > 0.0f) ? frsq(q1) : 0.0f;
    float c0 = (q0 > 0.0f) ? mc0 * i0 : 1.0f;
    float s0v = ms0 * i0;
    float c1 = (q1 > 0.0f) ? mc1 * i1 : 1.0f;
    float s1v = ms1 * i1;
    size_t obase = (size_t)b * FD + f;
    float2 xr = *(const float2*)(x_real + obase);
    float2 xi = *(const float2*)(x_imag + obase);
    float2 outr = make_float2((1.0f - a) * xr.x + a * (mr0 * c0),
                              (1.0f - a) * xr.y + a * (mr1 * c1));
    float2 outi = make_float2((1.0f - a) * xi.x + a * (mr0 * s0v),
                              (1.0f - a) * xi.y + a * (mr1 * s1v));
    *(float2*)(out + obase) = outr;
    *(float2*)(out + (size_t)BQ * FD + obase) = outi;
}

extern "C" void kernel_launch(void* const* d_in, const int* in_sizes, int n_in,
                              void* d_out, int out_size, void* d_ws, size_t ws_size,
                              hipStream_t stream) {
    const float* x_real   = (const float*)d_in[0];
    const float* x_imag   = (const float*)d_in[1];
    const float* att_real = (const float*)d_in[2];
    const float* att_imag = (const float*)d_in[3];
    const float* alpha    = (const float*)d_in[4];
    float* out = (float*)d_out;

    normalize_kernel<<<NDB / 16, 256, 0, stream>>>(x_real, x_imag, att_real, att_imag);
    gemm_mfma<<<NTILES, 256, 0, stream>>>();
    topk_agg_kernel<<<BQ, 256, 0, stream>>>(x_real, x_imag, att_real, att_imag, alpha, out);
}

// Round 15
// 376.649 us; speedup vs baseline: 1.0613x; 1.0613x over previous
//
#include <hip/hip_runtime.h>
#include <math.h>

#define BQ   4096
#define FD   512
#define NATT 8192
#define NDB  (BQ + NATT)   // 12288
#define DD   (2 * FD)      // 1024
#define KTOP 32
#define EPSF 1e-7f

#define QT   32            // 4096/128 query tiles
#define NT   96            // 12288/128 col-tiles per row for g_tmax
// tiles: att region 32x64 = 2048, Q-Q upper triangle incl diag = 528
#define NTILES (2048 + 528)

typedef __attribute__((ext_vector_type(8))) short bf16x8;
typedef __attribute__((ext_vector_type(8))) unsigned short u16x8;
typedef __attribute__((ext_vector_type(4))) float f32x4;

// Packed pre-tiled db: [panel(96,128-row)][kchunk(32)][hi|lo(2)][kc(4)][row(128)][8]
__device__ unsigned short g_pk[(size_t)NDB * DD * 2];  // 48 MB
__device__ float g_sims[(size_t)BQ * NDB];             // 201 MB
__device__ float g_tmax[(size_t)BQ * NT];              // 4.5 MB per-(row,128-tile) maxima

__device__ __forceinline__ unsigned fkey(unsigned u) {
    return u ^ (unsigned)(((int)u >> 31) | 0x80000000);  // monotonic float->uint
}
__device__ __forceinline__ unsigned short f2bf(float f) {   // RNE f32->bf16
    unsigned u = __float_as_uint(f);
    return (unsigned short)((u + 0x7FFFu + ((u >> 16) & 1u)) >> 16);
}
__device__ __forceinline__ float bf2f(unsigned short h) {
    return __uint_as_float((unsigned)h << 16);
}
__device__ __forceinline__ float frsq(float x) {
#if __has_builtin(__builtin_amdgcn_rsqf)
    return __builtin_amdgcn_rsqf(x);
#else
    return rsqrtf(x);
#endif
}
__device__ __forceinline__ void gld16(const void* g, void* l) {
    __builtin_amdgcn_global_load_lds(
        (const __attribute__((address_space(1))) void*)g,
        (__attribute__((address_space(3))) void*)l, 16, 0, 0);
}

// ---------------- 1. L2-normalize db rows, emit packed bf16 hi/lo ------------
// Block = 16 consecutive rows. Thread (r=t>>4, l16=t&15) owns 32 re + 32 im
// elements of row r.  Stores are ushort8 (16B); the 4 rows of a wave write
// adjacent 16B chunks per (kchunk,hl,kc) -> coalesced 64B transactions.
__global__ __launch_bounds__(256) void normalize_kernel(
        const float* __restrict__ x_real, const float* __restrict__ x_imag,
        const float* __restrict__ att_real, const float* __restrict__ att_imag) {
    int t = threadIdx.x;
    int r = t >> 4;             // 0..15 row within block (4 per wave)
    int l16 = t & 15;           // 16 threads per row
    int row = blockIdx.x * 16 + r;
    const float *re, *im;
    if (row < BQ) { re = x_real + (size_t)row * FD;          im = x_imag + (size_t)row * FD; }
    else          { re = att_real + (size_t)(row - BQ) * FD; im = att_imag + (size_t)(row - BQ) * FD; }

    float4 vre[8], vim[8];
    float ss = 0.0f;
#pragma unroll
    for (int i = 0; i < 8; ++i) {
        vre[i] = *(const float4*)(re + l16 * 32 + i * 4);
        vim[i] = *(const float4*)(im + l16 * 32 + i * 4);
        ss += vre[i].x * vre[i].x + vre[i].y * vre[i].y + vre[i].z * vre[i].z + vre[i].w * vre[i].w;
        ss += vim[i].x * vim[i].x + vim[i].y * vim[i].y + vim[i].z * vim[i].z + vim[i].w * vim[i].w;
    }
#pragma unroll
    for (int o = 1; o < 16; o <<= 1) ss += __shfl_xor(ss, o);   // 16-lane row reduce
    float ninv = frsq(ss);   // 1/||v||

    // emit 32 els (one kchunk) of hi/lo into the pk layout
    auto emit = [&](const float4* v, int kchunk) {
        unsigned short hi[32], lo[32];
#pragma unroll
        for (int i = 0; i < 8; ++i) {
            float vals[4] = {v[i].x, v[i].y, v[i].z, v[i].w};
#pragma unroll
            for (int j = 0; j < 4; ++j) {
                float nv = vals[j] * ninv;
                unsigned short h = f2bf(nv);
                hi[i * 4 + j] = h;
                lo[i * 4 + j] = f2bf(nv - bf2f(h));
            }
        }
        size_t cb = ((size_t)((row >> 7) * 32 + kchunk) * 2) * 4096 + (size_t)(row & 127) * 8;
#pragma unroll
        for (int kc = 0; kc < 4; ++kc) {
            *(u16x8*)(g_pk + cb + kc * 1024)        = *(u16x8*)&hi[kc * 8];   // hl=0
            *(u16x8*)(g_pk + cb + 4096 + kc * 1024) = *(u16x8*)&lo[kc * 8];   // hl=1
        }
    };
    emit(vre, l16);         // re part: k in [l16*32, l16*32+32)  -> kchunk l16
    emit(vim, 16 + l16);    // im part: k in [512+l16*32, ...)    -> kchunk 16+l16
}

// ---------------- 2. sims via bf16x3 MFMA + per-(row,tile) maxima ------------
// 128x128 tile, BK=32, 4 waves x (4x4) 16x16x32 fragments.  Q-Q region is
// symmetric: upper triangle computed, transpose written from the accumulator.
// Default block order (no XCD swizzle — measured: swizzle doubles HBM FETCH).
// Epilogue emits per-(row,128-tile) maxima for the topk threshold.
__global__ __launch_bounds__(256) void gemm_mfma() {
    __shared__ unsigned short smem[4 * 4096];
    const int t = threadIdx.x;
    const int lane = t & 63, wid = t >> 6;
    const int wr = wid >> 1, wc = wid & 1;
    const int kc = lane >> 4, fr = lane & 15;

    // unrank tile id -> (bm, bn), mirror flag
    int tid = blockIdx.x;
    int bm, bn; bool mirror = false;
    if (tid < 2048) { bm = tid >> 6; bn = QT + (tid & 63); }
    else {
        int t2 = tid - 2048;      // upper-triangle rank (row-major, incl diag)
        int r = 0, off = 0;
        while (t2 >= off + (QT - r)) { off += QT - r; ++r; }   // <=32 iters, uniform
        bm = r; bn = r + (t2 - off);
        mirror = (bn != bm);
    }

    f32x4 acc[4][4];
#pragma unroll
    for (int m = 0; m < 4; ++m)
#pragma unroll
        for (int n = 0; n < 4; ++n) acc[m][n] = (f32x4){0.f, 0.f, 0.f, 0.f};

    for (int c = 0; c < 32; ++c) {   // k0 = 32*c
        const unsigned short* apk = g_pk + ((size_t)(bm * 32 + c)) * 8192;
        const unsigned short* bpk = g_pk + ((size_t)(bn * 32 + c)) * 8192;
#pragma unroll
        for (int i = 0; i < 4; ++i) {
            int s = t + i * 256;                       // 0..1023 16B slots
            gld16(apk + (size_t)s * 8, &smem[s * 8]);
            gld16(bpk + (size_t)s * 8, &smem[8192 + s * 8]);
        }
        __syncthreads();

        bf16x8 ah[4], al[4], bh[4], bl[4];
#pragma unroll
        for (int m = 0; m < 4; ++m) {
            int ra = wr * 64 + m * 16 + fr;
            ah[m] = *(const bf16x8*)&smem[(kc * 128 + ra) * 8];
            al[m] = *(const bf16x8*)&smem[4096 + (kc * 128 + ra) * 8];
            int rb = wc * 64 + m * 16 + fr;
            bh[m] = *(const bf16x8*)&smem[8192 + (kc * 128 + rb) * 8];
            bl[m] = *(const bf16x8*)&smem[12288 + (kc * 128 + rb) * 8];
        }
#pragma unroll
        for (int m = 0; m < 4; ++m)
#pragma unroll
            for (int n = 0; n < 4; ++n) {
                acc[m][n] = __builtin_amdgcn_mfma_f32_16x16x32_bf16(ah[m], bh[n], acc[m][n], 0, 0, 0);
                acc[m][n] = __builtin_amdgcn_mfma_f32_16x16x32_bf16(ah[m], bl[n], acc[m][n], 0, 0, 0);
                acc[m][n] = __builtin_amdgcn_mfma_f32_16x16x32_bf16(al[m], bh[n], acc[m][n], 0, 0, 0);
            }
        __syncthreads();
    }
    // normal epilogue: C/D layout col=lane&15, row=(lane>>4)*4+j
    const int crow0 = bm * 128 + wr * 64 + kc * 4;
    const int ccol0 = bn * 128 + wc * 64 + fr;
#pragma unroll
    for (int m = 0; m < 4; ++m)
#pragma unroll
        for (int n = 0; n < 4; ++n)
#pragma unroll
            for (int j = 0; j < 4; ++j)
                g_sims[(size_t)(crow0 + m * 16 + j) * NDB + ccol0 + n * 16] = acc[m][n][j];

    if (mirror) {
        // transposed tile: per lane & frag 4 consecutive cols (j) -> one float4
#pragma unroll
        for (int m = 0; m < 4; ++m)
#pragma unroll
            for (int n = 0; n < 4; ++n) {
                size_t r = (size_t)(bn * 128 + wc * 64 + n * 16 + fr);
                size_t cix = (size_t)(bm * 128 + wr * 64 + m * 16 + kc * 4);
                *(f32x4*)&g_sims[r * NDB + cix] = acc[m][n];
            }
    }

    // --- per-row (and per-col if mirrored) tile maxima for topk threshold ---
    float* rowhalf = (float*)smem;          // [128][2]
    float* colhalf = (float*)smem + 256;    // [128][2]
#pragma unroll
    for (int m = 0; m < 4; ++m)
#pragma unroll
        for (int j = 0; j < 4; ++j) {
            float v = fmaxf(fmaxf(acc[m][0][j], acc[m][1][j]),
                            fmaxf(acc[m][2][j], acc[m][3][j]));
#pragma unroll
            for (int o = 1; o < 16; o <<= 1) v = fmaxf(v, __shfl_xor(v, o));
            if (fr == 0) rowhalf[(wr * 64 + m * 16 + kc * 4 + j) * 2 + wc] = v;
        }
    if (mirror) {
#pragma unroll
        for (int n = 0; n < 4; ++n) {
            float v = acc[0][n][0];
#pragma unroll
            for (int m = 0; m < 4; ++m)
#pragma unroll
                for (int j = 0; j < 4; ++j) v = fmaxf(v, acc[m][n][j]);
            v = fmaxf(v, __shfl_xor(v, 16));
            v = fmaxf(v, __shfl_xor(v, 32));
            if (kc == 0) colhalf[(wc * 64 + n * 16 + fr) * 2 + wr] = v;
        }
    }
    __syncthreads();
    if (t < 128) {
        g_tmax[(size_t)(bm * 128 + t) * NT + bn] = fmaxf(rowhalf[t * 2], rowhalf[t * 2 + 1]);
        if (mirror)
            g_tmax[(size_t)(bn * 128 + t) * NT + bm] = fmaxf(colhalf[t * 2], colhalf[t * 2 + 1]);
    }
}

// ------- 3+4 fused: parallel-rank T + tile-skipping collect + agg ------------
// T = 32nd-largest of the row's 96 tile maxima (parallel rank).  Tiles with
// tmax < T cannot contain a candidate -> stream only qualifying tiles
// (~35-50 of 96, 512B contiguous each).  Candidates -> 64-lane bitonic sort
// (exact numpy tie semantics); exact fallbacks beyond 64/512.
__global__ __launch_bounds__(256) void topk_agg_kernel(
        const float* __restrict__ x_real, const float* __restrict__ x_imag,
        const float* __restrict__ att_real, const float* __restrict__ att_imag,
        const float* __restrict__ alpha_p, float* __restrict__ out) {
    __shared__ float stm[96];
    __shared__ unsigned char tlist[96];
    __shared__ unsigned long long cand[512];
    __shared__ int s_idx[KTOP];
    __shared__ unsigned s_cnt;
    __shared__ int s_ntile;
    __shared__ float s_T;
    __shared__ unsigned long long s_red[4];
    __shared__ unsigned long long s_last;
    int b = blockIdx.x, t = threadIdx.x;
    int wave = t >> 6, lane = t & 63;

    if (t < 96) stm[t] = g_tmax[(size_t)b * NT + t];
    if (t == 0) { s_cnt = 0; s_ntile = 0; }
    __syncthreads();

    // parallel rank: thread t's value has rank #{i: v_i>v || (v_i==v && i<t)}
    if (t < 96) {
        float v = stm[t];
        int cnt = 0;
        for (int i = 0; i < 96; ++i) {
            float o = stm[i];
            cnt += (o > v) || (o == v && i < t);
        }
        if (cnt == KTOP - 1) s_T = v;   // exactly one thread has rank 31
    }
    __syncthreads();
    const float T = s_T;

    // qualifying tile list (tmax >= T); >= 32 entries by construction
    if (t < 96 && stm[t] >= T) {
        int p = atomicAdd(&s_ntile, 1);
        tlist[p] = (unsigned char)t;
    }
    __syncthreads();
    const int ntile = s_ntile;

    // stream only qualifying tiles: 8 tiles/iter, 32 lanes x float4 per tile
    const float* rowp = g_sims + (size_t)b * NDB;
    for (int base = 0; base < ntile; base += 8) {
        int ti = base + (t >> 5);
        if (ti < ntile) {
            int tile = tlist[ti];
            int c4 = (t & 31) * 4;
            float4 v = *(const float4*)(rowp + tile * 128 + c4);
            int gidx = tile * 128 + c4;
            if (v.x >= T) { unsigned p = atomicAdd(&s_cnt, 1u); if (p < 512) cand[p] = ((unsigned long long)fkey(__float_as_uint(v.x)) << 32) | (unsigned)(~(gidx + 0)); }
            if (v.y >= T) { unsigned p = atomicAdd(&s_cnt, 1u); if (p < 512) cand[p] = ((unsigned long long)fkey(__float_as_uint(v.y)) << 32) | (unsigned)(~(gidx + 1)); }
            if (v.z >= T) { unsigned p = atomicAdd(&s_cnt, 1u); if (p < 512) cand[p] = ((unsigned long long)fkey(__float_as_uint(v.z)) << 32) | (unsigned)(~(gidx + 2)); }
            if (v.w >= T) { unsigned p = atomicAdd(&s_cnt, 1u); if (p < 512) cand[p] = ((unsigned long long)fkey(__float_as_uint(v.w)) << 32) | (unsigned)(~(gidx + 3)); }
        }
    }
    __syncthreads();

    int c = (int)s_cnt;
    if (c <= 64) {
        if (wave == 0) {
            unsigned long long vv = (lane < c) ? cand[lane] : 0ull;
#pragma unroll
            for (int k = 2; k <= 64; k <<= 1)
#pragma unroll
                for (int j = k >> 1; j > 0; j >>= 1) {
                    unsigned long long o = __shfl_xor(vv, j);
                    bool lower = (lane & j) == 0;
                    bool desc  = (lane & k) == 0;
                    bool keepmax = (lower == desc);
                    vv = keepmax ? (vv > o ? vv : o) : (vv < o ? vv : o);
                }
            if (lane < KTOP) s_idx[lane] = (int)(~(unsigned)vv);
        }
    } else if (c <= 512) {
        if (wave == 0) {   // serial extraction over <=512 cands
            for (int it = 0; it < KTOP; ++it) {
                unsigned long long m = 0;
                for (int i = lane; i < c; i += 64) m = cand[i] > m ? cand[i] : m;
#pragma unroll
                for (int o = 32; o > 0; o >>= 1) {
                    unsigned long long x = __shfl_xor(m, o);
                    m = x > m ? x : m;
                }
                if (lane == 0) s_idx[it] = (int)(~(unsigned)m);
                for (int i = lane; i < c; i += 64) if (cand[i] == m) cand[i] = 0;
            }
        }
    } else {
        // never expected: exact 32x re-stream extraction over the full row
        const float4* row4 = (const float4*)rowp;
        unsigned long long last = ~0ull;
        for (int it = 0; it < KTOP; ++it) {
            unsigned long long m = 0;
            for (int i = 0; i < 12; ++i) {
                float4 v = row4[t + i * 256];
                int base = 4 * (t + i * 256);
                unsigned long long k;
                k = ((unsigned long long)fkey(__float_as_uint(v.x)) << 32) | (unsigned)(~(base + 0)); if (k < last && k > m) m = k;
                k = ((unsigned long long)fkey(__float_as_uint(v.y)) << 32) | (unsigned)(~(base + 1)); if (k < last && k > m) m = k;
                k = ((unsigned long long)fkey(__float_as_uint(v.z)) << 32) | (unsigned)(~(base + 2)); if (k < last && k > m) m = k;
                k = ((unsigned long long)fkey(__float_as_uint(v.w)) << 32) | (unsigned)(~(base + 3)); if (k < last && k > m) m = k;
            }
#pragma unroll
            for (int o = 32; o > 0; o >>= 1) {
                unsigned long long x = __shfl_xor(m, o);
                m = x > m ? x : m;
            }
            if (lane == 0) s_red[wave] = m;
            __syncthreads();
            if (t == 0) {
                unsigned long long w = s_red[0];
#pragma unroll
                for (int i = 1; i < 4; ++i) w = s_red[i] > w ? s_red[i] : w;
                s_idx[it] = (int)(~(unsigned)w);
                s_last = w;
            }
            __syncthreads();
            last = s_last;
        }
    }
    __syncthreads();

    // ---- aggregation: circular mean over the 32 neighbors + blend ----
    float a = alpha_p[0];
    a = fminf(fmaxf(a, 0.0f), 1.0f);
    int f = 2 * t;
    float sr0 = 0, sc0 = 0, ss0 = 0, sr1 = 0, sc1 = 0, ss1 = 0;
    for (int k = 0; k < KTOP; ++k) {
        int idx = s_idx[k];
        const float *re, *im;
        if (idx < BQ) { re = x_real + (size_t)idx * FD;          im = x_imag + (size_t)idx * FD; }
        else          { re = att_real + (size_t)(idx - BQ) * FD; im = att_imag + (size_t)(idx - BQ) * FD; }
        float2 vr = *(const float2*)(re + f);
        float2 vi = *(const float2*)(im + f);
        float s0 = vr.x * vr.x + vi.x * vi.x;
        if (s0 > 0.0f) {
            float iv = frsq(s0);
            sr0 += s0 * iv; sc0 += vr.x * iv; ss0 += vi.x * iv;
        } else sc0 += 1.0f;                     // atan2(0,0)=0
        float s1 = vr.y * vr.y + vi.y * vi.y;
        if (s1 > 0.0f) {
            float iv = frsq(s1);
            sr1 += s1 * iv; sc1 += vr.y * iv; ss1 += vi.y * iv;
        } else sc1 += 1.0f;
    }
    const float inv = 1.0f / KTOP;
    float mr0 = sr0 * inv + EPSF, mc0 = sc0 * inv, ms0 = ss0 * inv;
    float mr1 = sr1 * inv + EPSF, mc1 = sc1 * inv, ms1 = ss1 * inv;
    float q0 = mc0 * mc0 + ms0 * ms0;
    float q1 = mc1 * mc1 + ms1 * ms1;
    float i0 = (q0 > 0.0f) ? frsq(q0) : 0.0f;   // q==0 -> phi=0 -> cos=1,sin=0
    float i1 = (q1 > 0.0f) ? frsq(q1) : 0.0f;
    float c0 = (q0 > 0.0f) ? mc0 * i0 : 1.0f;
    float s0v = ms0 * i0;
    float c1 = (q1 > 0.0f) ? mc1 * i1 : 1.0f;
    float s1v = ms1 * i1;
    size_t obase = (size_t)b * FD + f;
    float2 xr = *(const float2*)(x_real + obase);
    float2 xi = *(const float2*)(x_imag + obase);
    float2 outr = make_float2((1.0f - a) * xr.x + a * (mr0 * c0),
                              (1.0f - a) * xr.y + a * (mr1 * c1));
    float2 outi = make_float2((1.0f - a) * xi.x + a * (mr0 * s0v),
                              (1.0f - a) * xi.y + a * (mr1 * s1v));
    *(float2*)(out + obase) = outr;
    *(float2*)(out + (size_t)BQ * FD + obase) = outi;
}

extern "C" void kernel_launch(void* const* d_in, const int* in_sizes, int n_in,
                              void* d_out, int out_size, void* d_ws, size_t ws_size,
                              hipStream_t stream) {
    const float* x_real   = (const float*)d_in[0];
    const float* x_imag   = (const float*)d_in[1];
    const float* att_real = (const float*)d_in[2];
    const float* att_imag = (const float*)d_in[3];
    const float* alpha    = (const float*)d_in[4];
    float* out = (float*)d_out;

    normalize_kernel<<<NDB / 16, 256, 0, stream>>>(x_real, x_imag, att_real, att_imag);
    gemm_mfma<<<NTILES, 256, 0, stream>>>();
    topk_agg_kernel<<<BQ, 256, 0, stream>>>(x_real, x_imag, att_real, att_imag, alpha, out);
}

// Round 16
// 332.951 us; speedup vs baseline: 1.2006x; 1.1312x over previous
//
#include <hip/hip_runtime.h>
#include <math.h>

#define BQ   4096
#define FD   512
#define NATT 8192
#define NDB  (BQ + NATT)   // 12288
#define DD   (2 * FD)      // 1024
#define KTOP 32
#define EPSF 1e-7f
#define DEL2 0.004f        // 2*delta: elementwise |sims_hi - exact| <= 0.002 (Hoeffding-safe)

#define QT   32            // 4096/128 query tiles
#define NT   96            // 12288/128 col-tiles per row for g_tmax
// tiles: att region 32x64 = 2048, Q-Q upper triangle incl diag = 528
#define NTILES (2048 + 528)

typedef __attribute__((ext_vector_type(8))) short bf16x8;
typedef __attribute__((ext_vector_type(8))) unsigned short u16x8;
typedef __attribute__((ext_vector_type(4))) float f32x4;

// Packed pre-tiled db (hi only): [panel(96)][kchunk(32)][kc(4)][row(128)][8]
__device__ unsigned short g_pk[(size_t)NDB * DD];      // 24 MB
__device__ float g_sims[(size_t)BQ * NDB];             // 201 MB (hi-only sims)
__device__ float g_tmax[(size_t)BQ * NT];              // per-(row,128-tile) maxima of sims_hi
__device__ float g_ninv[NDB];                          // 1/||row||

__device__ __forceinline__ unsigned fkey(unsigned u) {
    return u ^ (unsigned)(((int)u >> 31) | 0x80000000);  // monotonic float->uint
}
__device__ __forceinline__ float unfkey(unsigned fk) {
    unsigned u = (fk & 0x80000000u) ? (fk ^ 0x80000000u) : ~fk;
    return __uint_as_float(u);
}
__device__ __forceinline__ unsigned short f2bf(float f) {   // RNE f32->bf16
    unsigned u = __float_as_uint(f);
    return (unsigned short)((u + 0x7FFFu + ((u >> 16) & 1u)) >> 16);
}
__device__ __forceinline__ float frsq(float x) {
#if __has_builtin(__builtin_amdgcn_rsqf)
    return __builtin_amdgcn_rsqf(x);
#else
    return rsqrtf(x);
#endif
}
__device__ __forceinline__ void gld16(const void* g, void* l) {
    __builtin_amdgcn_global_load_lds(
        (const __attribute__((address_space(1))) void*)g,
        (__attribute__((address_space(3))) void*)l, 16, 0, 0);
}

// ---------------- 1. L2-normalize db rows, emit packed bf16 hi + 1/norm ------
__global__ __launch_bounds__(256) void normalize_kernel(
        const float* __restrict__ x_real, const float* __restrict__ x_imag,
        const float* __restrict__ att_real, const float* __restrict__ att_imag) {
    int t = threadIdx.x;
    int r = t >> 4;             // 0..15 row within block
    int l16 = t & 15;           // 16 threads per row
    int row = blockIdx.x * 16 + r;
    const float *re, *im;
    if (row < BQ) { re = x_real + (size_t)row * FD;          im = x_imag + (size_t)row * FD; }
    else          { re = att_real + (size_t)(row - BQ) * FD; im = att_imag + (size_t)(row - BQ) * FD; }

    float4 vre[8], vim[8];
    float ss = 0.0f;
#pragma unroll
    for (int i = 0; i < 8; ++i) {
        vre[i] = *(const float4*)(re + l16 * 32 + i * 4);
        vim[i] = *(const float4*)(im + l16 * 32 + i * 4);
        ss += vre[i].x * vre[i].x + vre[i].y * vre[i].y + vre[i].z * vre[i].z + vre[i].w * vre[i].w;
        ss += vim[i].x * vim[i].x + vim[i].y * vim[i].y + vim[i].z * vim[i].z + vim[i].w * vim[i].w;
    }
#pragma unroll
    for (int o = 1; o < 16; o <<= 1) ss += __shfl_xor(ss, o);   // 16-lane row reduce
    float ninv = frsq(ss);   // 1/||v||
    if (l16 == 0) g_ninv[row] = ninv;

    auto emit = [&](const float4* v, int kchunk) {
        unsigned short hi[32];
#pragma unroll
        for (int i = 0; i < 8; ++i) {
            float vals[4] = {v[i].x, v[i].y, v[i].z, v[i].w};
#pragma unroll
            for (int j = 0; j < 4; ++j) hi[i * 4 + j] = f2bf(vals[j] * ninv);
        }
        size_t cb = ((size_t)((row >> 7) * 32 + kchunk)) * 4096 + (size_t)(row & 127) * 8;
#pragma unroll
        for (int kc = 0; kc < 4; ++kc)
            *(u16x8*)(g_pk + cb + kc * 1024) = *(u16x8*)&hi[kc * 8];
    };
    emit(vre, l16);         // re part -> kchunk l16
    emit(vim, 16 + l16);    // im part -> kchunk 16+l16
}

// ---------------- 2. sims_hi via 1-term bf16 MFMA + per-(row,tile) maxima ----
// 128x128 tile, BK=32, 4 waves x (4x4) frags, 16 MFMA/wave-step.  LDS 16 KB.
// Q-Q symmetric: upper triangle computed, transpose from accumulator.
__global__ __launch_bounds__(256) void gemm_mfma() {
    __shared__ unsigned short smem[2 * 4096];
    const int t = threadIdx.x;
    const int lane = t & 63, wid = t >> 6;
    const int wr = wid >> 1, wc = wid & 1;
    const int kc = lane >> 4, fr = lane & 15;

    int tid = blockIdx.x;
    int bm, bn; bool mirror = false;
    if (tid < 2048) { bm = tid >> 6; bn = QT + (tid & 63); }
    else {
        int t2 = tid - 2048;
        int r = 0, off = 0;
        while (t2 >= off + (QT - r)) { off += QT - r; ++r; }
        bm = r; bn = r + (t2 - off);
        mirror = (bn != bm);
    }

    f32x4 acc[4][4];
#pragma unroll
    for (int m = 0; m < 4; ++m)
#pragma unroll
        for (int n = 0; n < 4; ++n) acc[m][n] = (f32x4){0.f, 0.f, 0.f, 0.f};

    for (int c = 0; c < 32; ++c) {   // k0 = 32*c
        const unsigned short* apk = g_pk + ((size_t)(bm * 32 + c)) * 4096;
        const unsigned short* bpk = g_pk + ((size_t)(bn * 32 + c)) * 4096;
#pragma unroll
        for (int i = 0; i < 2; ++i) {
            int s = t + i * 256;                       // 0..511 16B slots
            gld16(apk + (size_t)s * 8, &smem[s * 8]);
            gld16(bpk + (size_t)s * 8, &smem[4096 + s * 8]);
        }
        __syncthreads();

        bf16x8 ah[4], bh[4];
#pragma unroll
        for (int m = 0; m < 4; ++m) {
            int ra = wr * 64 + m * 16 + fr;
            ah[m] = *(const bf16x8*)&smem[(kc * 128 + ra) * 8];
            int rb = wc * 64 + m * 16 + fr;
            bh[m] = *(const bf16x8*)&smem[4096 + (kc * 128 + rb) * 8];
        }
#pragma unroll
        for (int m = 0; m < 4; ++m)
#pragma unroll
            for (int n = 0; n < 4; ++n)
                acc[m][n] = __builtin_amdgcn_mfma_f32_16x16x32_bf16(ah[m], bh[n], acc[m][n], 0, 0, 0);
        __syncthreads();
    }
    // epilogue: C/D layout col=lane&15, row=(lane>>4)*4+j
    const int crow0 = bm * 128 + wr * 64 + kc * 4;
    const int ccol0 = bn * 128 + wc * 64 + fr;
#pragma unroll
    for (int m = 0; m < 4; ++m)
#pragma unroll
        for (int n = 0; n < 4; ++n)
#pragma unroll
            for (int j = 0; j < 4; ++j)
                g_sims[(size_t)(crow0 + m * 16 + j) * NDB + ccol0 + n * 16] = acc[m][n][j];

    if (mirror) {
#pragma unroll
        for (int m = 0; m < 4; ++m)
#pragma unroll
            for (int n = 0; n < 4; ++n) {
                size_t r = (size_t)(bn * 128 + wc * 64 + n * 16 + fr);
                size_t cix = (size_t)(bm * 128 + wr * 64 + m * 16 + kc * 4);
                *(f32x4*)&g_sims[r * NDB + cix] = acc[m][n];
            }
    }

    // --- per-row (and per-col if mirrored) tile maxima ---
    float* rowhalf = (float*)smem;          // [128][2]
    float* colhalf = (float*)smem + 256;    // [128][2]
#pragma unroll
    for (int m = 0; m < 4; ++m)
#pragma unroll
        for (int j = 0; j < 4; ++j) {
            float v = fmaxf(fmaxf(acc[m][0][j], acc[m][1][j]),
                            fmaxf(acc[m][2][j], acc[m][3][j]));
#pragma unroll
            for (int o = 1; o < 16; o <<= 1) v = fmaxf(v, __shfl_xor(v, o));
            if (fr == 0) rowhalf[(wr * 64 + m * 16 + kc * 4 + j) * 2 + wc] = v;
        }
    if (mirror) {
#pragma unroll
        for (int n = 0; n < 4; ++n) {
            float v = acc[0][n][0];
#pragma unroll
            for (int m = 0; m < 4; ++m)
#pragma unroll
                for (int j = 0; j < 4; ++j) v = fmaxf(v, acc[m][n][j]);
            v = fmaxf(v, __shfl_xor(v, 16));
            v = fmaxf(v, __shfl_xor(v, 32));
            if (kc == 0) colhalf[(wc * 64 + n * 16 + fr) * 2 + wr] = v;
        }
    }
    __syncthreads();
    if (t < 128) {
        g_tmax[(size_t)(bm * 128 + t) * NT + bn] = fmaxf(rowhalf[t * 2], rowhalf[t * 2 + 1]);
        if (mirror)
            g_tmax[(size_t)(bn * 128 + t) * NT + bm] = fmaxf(colhalf[t * 2], colhalf[t * 2 + 1]);
    }
}

// ------- 3+4 fused: margin-threshold collect + exact rescore + agg -----------
// sims_hi error bound delta=0.002 -> candidates = {hi >= T32 - 2d}; sorted;
// sure-in = hi > V32+2d (guaranteed top-32 members); ambiguous band rescored
// EXACTLY in fp32 from raw inputs (coalesced, L3-resident); final set = sure
// + top-(32-S) rescored.  Deterministic (ballot-prefix classify).  Fallbacks:
// block-extract-64 for c>64; rescore-all + serial extract on overflow.
__global__ __launch_bounds__(256) void topk_agg_kernel(
        const float* __restrict__ x_real, const float* __restrict__ x_imag,
        const float* __restrict__ att_real, const float* __restrict__ att_imag,
        const float* __restrict__ alpha_p, float* __restrict__ out) {
    __shared__ float stm[96];
    __shared__ unsigned char tlist[96];
    __shared__ unsigned long long cand[1024];
    __shared__ unsigned long long skey[64];
    __shared__ unsigned long long rkey[64];
    __shared__ int ridx[64];
    __shared__ int s_idx[KTOP];
    __shared__ float qre[FD], qim[FD];
    __shared__ unsigned s_cnt;
    __shared__ int s_ntile, s_S, s_R;
    __shared__ float s_T, s_V32;
    __shared__ unsigned long long s_red[4];
    __shared__ unsigned long long s_last;
    int b = blockIdx.x, t = threadIdx.x;
    int wave = t >> 6, lane = t & 63;

    if (t < 96) stm[t] = g_tmax[(size_t)b * NT + t];
    if (t < 128) *(float4*)&qre[t * 4] = *(const float4*)(x_real + (size_t)b * FD + t * 4);
    else         *(float4*)&qim[(t - 128) * 4] = *(const float4*)(x_imag + (size_t)b * FD + (t - 128) * 4);
    if (t == 0) { s_cnt = 0; s_ntile = 0; s_S = 0; s_R = 0; }
    __syncthreads();

    // T = 32nd-largest tile max (parallel rank)
    if (t < 96) {
        float v = stm[t];
        int cnt = 0;
        for (int i = 0; i < 96; ++i) {
            float o = stm[i];
            cnt += (o > v) || (o == v && i < t);
        }
        if (cnt == KTOP - 1) s_T = v;
    }
    __syncthreads();
    const float Tm = s_T - DEL2;      // margin threshold

    if (t < 96 && stm[t] >= Tm) { int p = atomicAdd(&s_ntile, 1); tlist[p] = (unsigned char)t; }
    __syncthreads();
    const int ntile = s_ntile;

    // stream qualifying tiles, collect candidates >= Tm
    const float* rowp = g_sims + (size_t)b * NDB;
    for (int base = 0; base < ntile; base += 8) {
        int ti = base + (t >> 5);
        if (ti < ntile) {
            int tile = tlist[ti];
            int c4 = (t & 31) * 4;
            float4 v = *(const float4*)(rowp + tile * 128 + c4);
            int gidx = tile * 128 + c4;
            if (v.x >= Tm) { unsigned p = atomicAdd(&s_cnt, 1u); if (p < 1024) cand[p] = ((unsigned long long)fkey(__float_as_uint(v.x)) << 32) | (unsigned)(~(gidx + 0)); }
            if (v.y >= Tm) { unsigned p = atomicAdd(&s_cnt, 1u); if (p < 1024) cand[p] = ((unsigned long long)fkey(__float_as_uint(v.y)) << 32) | (unsigned)(~(gidx + 1)); }
            if (v.z >= Tm) { unsigned p = atomicAdd(&s_cnt, 1u); if (p < 1024) cand[p] = ((unsigned long long)fkey(__float_as_uint(v.z)) << 32) | (unsigned)(~(gidx + 2)); }
            if (v.w >= Tm) { unsigned p = atomicAdd(&s_cnt, 1u); if (p < 1024) cand[p] = ((unsigned long long)fkey(__float_as_uint(v.w)) << 32) | (unsigned)(~(gidx + 3)); }
        }
    }
    __syncthreads();
    unsigned cnt_raw = s_cnt;
    int c = (int)cnt_raw; if (c > 1024) c = 1024;

    // sorted top-64 -> skey
    if (c <= 64) {
        if (wave == 0) {
            unsigned long long vv = (lane < c) ? cand[lane] : 0ull;
#pragma unroll
            for (int k = 2; k <= 64; k <<= 1)
#pragma unroll
                for (int j = k >> 1; j > 0; j >>= 1) {
                    unsigned long long o = __shfl_xor(vv, j);
                    bool lower = (lane & j) == 0;
                    bool desc  = (lane & k) == 0;
                    bool keepmax = (lower == desc);
                    vv = keepmax ? (vv > o ? vv : o) : (vv < o ? vv : o);
                }
            skey[lane] = vv;
        }
        __syncthreads();
    } else {
        unsigned long long last = ~0ull;
        for (int it = 0; it < 64; ++it) {
            unsigned long long m = 0;
            for (int i = t; i < c; i += 256) { unsigned long long k = cand[i]; if (k < last && k > m) m = k; }
#pragma unroll
            for (int o = 32; o > 0; o >>= 1) { unsigned long long x = __shfl_xor(m, o); m = x > m ? x : m; }
            if (lane == 0) s_red[wave] = m;
            __syncthreads();
            if (t == 0) {
                unsigned long long w = s_red[0];
#pragma unroll
                for (int i = 1; i < 4; ++i) w = s_red[i] > w ? s_red[i] : w;
                skey[it] = w; s_last = w;
            }
            __syncthreads();
            last = s_last;
        }
    }
    if (t == 0) s_V32 = unfkey((unsigned)(skey[31] >> 32));
    __syncthreads();
    const float V32 = s_V32;
    bool fallback = (cnt_raw > 1024);
    if (c > 64) {
        float v63 = unfkey((unsigned)(skey[63] >> 32));
        fallback = fallback || (v63 >= V32 - DEL2);
    }
    const float qninv = g_ninv[b];

    if (!fallback) {
        // classify sorted (descending) entries: sure prefix, ambiguous segment
        if (wave == 0) {
            unsigned long long k = skey[lane];
            float v = (k != 0) ? unfkey((unsigned)(k >> 32)) : -INFINITY;
            int idx = (int)(~(unsigned)k);
            bool sure = v > V32 + DEL2;
            bool amb  = !sure && v >= V32 - DEL2;
            unsigned long long smask = __ballot(sure);
            int S = __popcll(smask);
            if (sure) s_idx[lane] = idx;           // sure = prefix of ranks
            if (amb)  ridx[lane - S] = idx;        // ambiguous = next segment
            if (lane == 0) { s_S = S; }
            unsigned long long amask = __ballot(amb);
            if (lane == 0) { s_R = __popcll(amask); }
        }
        __syncthreads();
        int S = s_S, R = s_R;
        // exact fp32 rescore of ambiguous entries (one per wave, coalesced)
        for (int r = wave; r < R; r += 4) {
            int j = ridx[r];
            const float *dre, *dim_;
            if (j < BQ) { dre = x_real + (size_t)j * FD; dim_ = x_imag + (size_t)j * FD; }
            else        { dre = att_real + (size_t)(j - BQ) * FD; dim_ = att_imag + (size_t)(j - BQ) * FD; }
            float4 a0 = *(const float4*)&qre[lane * 8], a1 = *(const float4*)&qre[lane * 8 + 4];
            float4 b0 = *(const float4*)(dre + lane * 8), b1 = *(const float4*)(dre + lane * 8 + 4);
            float4 c0 = *(const float4*)&qim[lane * 8], c1 = *(const float4*)&qim[lane * 8 + 4];
            float4 d0 = *(const float4*)(dim_ + lane * 8), d1 = *(const float4*)(dim_ + lane * 8 + 4);
            float s = a0.x * b0.x + a0.y * b0.y + a0.z * b0.z + a0.w * b0.w
                    + a1.x * b1.x + a1.y * b1.y + a1.z * b1.z + a1.w * b1.w
                    + c0.x * d0.x + c0.y * d0.y + c0.z * d0.z + c0.w * d0.w
                    + c1.x * d1.x + c1.y * d1.y + c1.z * d1.z + c1.w * d1.w;
#pragma unroll
            for (int o = 32; o > 0; o >>= 1) s += __shfl_xor(s, o);
            float v = s * qninv * g_ninv[j];
            if (lane == 0) rkey[r] = ((unsigned long long)fkey(__float_as_uint(v)) << 32) | (unsigned)(~j);
        }
        __syncthreads();
        // top-(32-S) of rescored via wave0 bitonic
        if (wave == 0) {
            unsigned long long vv = (lane < R) ? rkey[lane] : 0ull;
#pragma unroll
            for (int k = 2; k <= 64; k <<= 1)
#pragma unroll
                for (int j = k >> 1; j > 0; j >>= 1) {
                    unsigned long long o = __shfl_xor(vv, j);
                    bool lower = (lane & j) == 0;
                    bool desc  = (lane & k) == 0;
                    bool keepmax = (lower == desc);
                    vv = keepmax ? (vv > o ? vv : o) : (vv < o ? vv : o);
                }
            if (lane < KTOP - S) s_idx[S + lane] = (int)(~(unsigned)vv);
        }
        __syncthreads();
    } else {
        // rescore ALL candidates exactly, then block-serial extract top-32
        for (int r = wave; r < c; r += 4) {
            int j = (int)(~(unsigned)cand[r]);
            const float *dre, *dim_;
            if (j < BQ) { dre = x_real + (size_t)j * FD; dim_ = x_imag + (size_t)j * FD; }
            else        { dre = att_real + (size_t)(j - BQ) * FD; dim_ = att_imag + (size_t)(j - BQ) * FD; }
            float4 a0 = *(const float4*)&qre[lane * 8], a1 = *(const float4*)&qre[lane * 8 + 4];
            float4 b0 = *(const float4*)(dre + lane * 8), b1 = *(const float4*)(dre + lane * 8 + 4);
            float4 c0 = *(const float4*)&qim[lane * 8], c1 = *(const float4*)&qim[lane * 8 + 4];
            float4 d0 = *(const float4*)(dim_ + lane * 8), d1 = *(const float4*)(dim_ + lane * 8 + 4);
            float s = a0.x * b0.x + a0.y * b0.y + a0.z * b0.z + a0.w * b0.w
                    + a1.x * b1.x + a1.y * b1.y + a1.z * b1.z + a1.w * b1.w
                    + c0.x * d0.x + c0.y * d0.y + c0.z * d0.z + c0.w * d0.w
                    + c1.x * d1.x + c1.y * d1.y + c1.z * d1.z + c1.w * d1.w;
#pragma unroll
            for (int o = 32; o > 0; o >>= 1) s += __shfl_xor(s, o);
            float v = s * qninv * g_ninv[j];
            if (lane == 0) cand[r] = ((unsigned long long)fkey(__float_as_uint(v)) << 32) | (unsigned)(~j);
        }
        __syncthreads();
        unsigned long long last = ~0ull;
        for (int it = 0; it < KTOP; ++it) {
            unsigned long long m = 0;
            for (int i = t; i < c; i += 256) { unsigned long long k = cand[i]; if (k < last && k > m) m = k; }
#pragma unroll
            for (int o = 32; o > 0; o >>= 1) { unsigned long long x = __shfl_xor(m, o); m = x > m ? x : m; }
            if (lane == 0) s_red[wave] = m;
            __syncthreads();
            if (t == 0) {
                unsigned long long w = s_red[0];
#pragma unroll
                for (int i = 1; i < 4; ++i) w = s_red[i] > w ? s_red[i] : w;
                s_idx[it] = (int)(~(unsigned)w); s_last = w;
            }
            __syncthreads();
            last = s_last;
        }
    }
    __syncthreads();

    // ---- aggregation: circular mean over the 32 neighbors + blend ----
    float a = alpha_p[0];
    a = fminf(fmaxf(a, 0.0f), 1.0f);
    int f = 2 * t;
    float sr0 = 0, sc0 = 0, ss0 = 0, sr1 = 0, sc1 = 0, ss1 = 0;
    for (int k = 0; k < KTOP; ++k) {
        int idx = s_idx[k];
        const float *re, *im;
        if (idx < BQ) { re = x_real + (size_t)idx * FD;          im = x_imag + (size_t)idx * FD; }
        else          { re = att_real + (size_t)(idx - BQ) * FD; im = att_imag + (size_t)(idx - BQ) * FD; }
        float2 vr = *(const float2*)(re + f);
        float2 vi = *(const float2*)(im + f);
        float s0 = vr.x * vr.x + vi.x * vi.x;
        if (s0 > 0.0f) {
            float iv = frsq(s0);
            sr0 += s0 * iv; sc0 += vr.x * iv; ss0 += vi.x * iv;
        } else sc0 += 1.0f;                     // atan2(0,0)=0
        float s1 = vr.y * vr.y + vi.y * vi.y;
        if (s1 > 0.0f) {
            float iv = frsq(s1);
            sr1 += s1 * iv; sc1 += vr.y * iv; ss1 += vi.y * iv;
        } else sc1 += 1.0f;
    }
    const float inv = 1.0f / KTOP;
    float mr0 = sr0 * inv + EPSF, mc0 = sc0 * inv, ms0 = ss0 * inv;
    float mr1 = sr1 * inv + EPSF, mc1 = sc1 * inv, ms1 = ss1 * inv;
    float q0 = mc0 * mc0 + ms0 * ms0;
    float q1 = mc1 * mc1 + ms1 * ms1;
    float i0 = (q0 > 0.0f) ? frsq(q0) : 0.0f;   // q==0 -> phi=0 -> cos=1,sin=0
    float i1 = (q1 > 0.0f) ? frsq(q1) : 0.0f;
    float c0v = (q0 > 0.0f) ? mc0 * i0 : 1.0f;
    float s0v = ms0 * i0;
    float c1v = (q1 > 0.0f) ? mc1 * i1 : 1.0f;
    float s1v = ms1 * i1;
    size_t obase = (size_t)b * FD + f;
    float2 xr = *(const float2*)(x_real + obase);
    float2 xi = *(const float2*)(x_imag + obase);
    float2 outr = make_float2((1.0f - a) * xr.x + a * (mr0 * c0v),
                              (1.0f - a) * xr.y + a * (mr1 * c1v));
    float2 outi = make_float2((1.0f - a) * xi.x + a * (mr0 * s0v),
                              (1.0f - a) * xi.y + a * (mr1 * s1v));
    *(float2*)(out + obase) = outr;
    *(float2*)(out + (size_t)BQ * FD + obase) = outi;
}

extern "C" void kernel_launch(void* const* d_in, const int* in_sizes, int n_in,
                              void* d_out, int out_size, void* d_ws, size_t ws_size,
                              hipStream_t stream) {
    const float* x_real   = (const float*)d_in[0];
    const float* x_imag   = (const float*)d_in[1];
    const float* att_real = (const float*)d_in[2];
    const float* att_imag = (const float*)d_in[3];
    const float* alpha    = (const float*)d_in[4];
    float* out = (float*)d_out;

    normalize_kernel<<<NDB / 16, 256, 0, stream>>>(x_real, x_imag, att_real, att_imag);
    gemm_mfma<<<NTILES, 256, 0, stream>>>();
    topk_agg_kernel<<<BQ, 256, 0, stream>>>(x_real, x_imag, att_real, att_imag, alpha, out);
}

// Round 17
// 319.068 us; speedup vs baseline: 1.2528x; 1.0435x over previous
//
#include <hip/hip_runtime.h>
#include <math.h>

#define BQ   4096
#define FD   512
#define NATT 8192
#define NDB  (BQ + NATT)   // 12288
#define DD   (2 * FD)      // 1024
#define KTOP 32
#define EPSF 1e-7f
#define DEL2 0.004f        // 2*delta margin (validated: exact selection at this bound)

#define QT   32            // 4096/128 query tiles
#define NT   96            // 12288/128 col-tiles per row for g_tmax
// tiles: att region 32x64 = 2048, Q-Q upper triangle incl diag = 528
#define NTILES (2048 + 528)

typedef __attribute__((ext_vector_type(8))) short bf16x8;
typedef __attribute__((ext_vector_type(8))) unsigned short u16x8;
typedef __attribute__((ext_vector_type(4))) float f32x4;

// Packed pre-tiled db (hi only): [panel(96)][kchunk(32)][kc(4)][row(128)][8]
__device__ unsigned short g_pk[(size_t)NDB * DD];      // 24 MB
__device__ float g_sims[(size_t)BQ * NDB];             // 201 MB (hi-only sims)
__device__ float g_tmax[(size_t)BQ * NT];              // per-(row,128-tile) maxima of sims_hi
__device__ float g_ninv[NDB];                          // 1/||row||
__device__ int   g_topk[BQ * KTOP];

__device__ __forceinline__ unsigned fkey(unsigned u) {
    return u ^ (unsigned)(((int)u >> 31) | 0x80000000);  // monotonic float->uint
}
__device__ __forceinline__ float unfkey(unsigned fk) {
    unsigned u = (fk & 0x80000000u) ? (fk ^ 0x80000000u) : ~fk;
    return __uint_as_float(u);
}
__device__ __forceinline__ unsigned short f2bf(float f) {   // RNE f32->bf16
    unsigned u = __float_as_uint(f);
    return (unsigned short)((u + 0x7FFFu + ((u >> 16) & 1u)) >> 16);
}
__device__ __forceinline__ float frsq(float x) {
#if __has_builtin(__builtin_amdgcn_rsqf)
    return __builtin_amdgcn_rsqf(x);
#else
    return rsqrtf(x);
#endif
}
__device__ __forceinline__ void gld16(const void* g, void* l) {
    __builtin_amdgcn_global_load_lds(
        (const __attribute__((address_space(1))) void*)g,
        (__attribute__((address_space(3))) void*)l, 16, 0, 0);
}

// descending 64-lane bitonic sort (verified network)
__device__ __forceinline__ unsigned long long bitonic64(unsigned long long vv, int lane) {
#pragma unroll
    for (int k = 2; k <= 64; k <<= 1)
#pragma unroll
        for (int j = k >> 1; j > 0; j >>= 1) {
            unsigned long long o = __shfl_xor(vv, j);
            bool lower = (lane & j) == 0;
            bool desc  = (lane & k) == 0;
            bool keepmax = (lower == desc);
            vv = keepmax ? (vv > o ? vv : o) : (vv < o ? vv : o);
        }
    return vv;
}

// ---------------- 1. L2-normalize db rows, emit packed bf16 hi + 1/norm ------
__global__ __launch_bounds__(256) void normalize_kernel(
        const float* __restrict__ x_real, const float* __restrict__ x_imag,
        const float* __restrict__ att_real, const float* __restrict__ att_imag) {
    int t = threadIdx.x;
    int r = t >> 4;
    int l16 = t & 15;
    int row = blockIdx.x * 16 + r;
    const float *re, *im;
    if (row < BQ) { re = x_real + (size_t)row * FD;          im = x_imag + (size_t)row * FD; }
    else          { re = att_real + (size_t)(row - BQ) * FD; im = att_imag + (size_t)(row - BQ) * FD; }

    float4 vre[8], vim[8];
    float ss = 0.0f;
#pragma unroll
    for (int i = 0; i < 8; ++i) {
        vre[i] = *(const float4*)(re + l16 * 32 + i * 4);
        vim[i] = *(const float4*)(im + l16 * 32 + i * 4);
        ss += vre[i].x * vre[i].x + vre[i].y * vre[i].y + vre[i].z * vre[i].z + vre[i].w * vre[i].w;
        ss += vim[i].x * vim[i].x + vim[i].y * vim[i].y + vim[i].z * vim[i].z + vim[i].w * vim[i].w;
    }
#pragma unroll
    for (int o = 1; o < 16; o <<= 1) ss += __shfl_xor(ss, o);
    float ninv = frsq(ss);
    if (l16 == 0) g_ninv[row] = ninv;

    auto emit = [&](const float4* v, int kchunk) {
        unsigned short hi[32];
#pragma unroll
        for (int i = 0; i < 8; ++i) {
            float vals[4] = {v[i].x, v[i].y, v[i].z, v[i].w};
#pragma unroll
            for (int j = 0; j < 4; ++j) hi[i * 4 + j] = f2bf(vals[j] * ninv);
        }
        size_t cb = ((size_t)((row >> 7) * 32 + kchunk)) * 4096 + (size_t)(row & 127) * 8;
#pragma unroll
        for (int kc = 0; kc < 4; ++kc)
            *(u16x8*)(g_pk + cb + kc * 1024) = *(u16x8*)&hi[kc * 8];
    };
    emit(vre, l16);
    emit(vim, 16 + l16);
}

// ---------------- 2. sims_hi via 1-term bf16 MFMA + per-(row,tile) maxima ----
__global__ __launch_bounds__(256) void gemm_mfma() {
    __shared__ unsigned short smem[2 * 4096];
    const int t = threadIdx.x;
    const int lane = t & 63, wid = t >> 6;
    const int wr = wid >> 1, wc = wid & 1;
    const int kc = lane >> 4, fr = lane & 15;

    int tid = blockIdx.x;
    int bm, bn; bool mirror = false;
    if (tid < 2048) { bm = tid >> 6; bn = QT + (tid & 63); }
    else {
        int t2 = tid - 2048;
        int r = 0, off = 0;
        while (t2 >= off + (QT - r)) { off += QT - r; ++r; }
        bm = r; bn = r + (t2 - off);
        mirror = (bn != bm);
    }

    f32x4 acc[4][4];
#pragma unroll
    for (int m = 0; m < 4; ++m)
#pragma unroll
        for (int n = 0; n < 4; ++n) acc[m][n] = (f32x4){0.f, 0.f, 0.f, 0.f};

    for (int c = 0; c < 32; ++c) {
        const unsigned short* apk = g_pk + ((size_t)(bm * 32 + c)) * 4096;
        const unsigned short* bpk = g_pk + ((size_t)(bn * 32 + c)) * 4096;
#pragma unroll
        for (int i = 0; i < 2; ++i) {
            int s = t + i * 256;
            gld16(apk + (size_t)s * 8, &smem[s * 8]);
            gld16(bpk + (size_t)s * 8, &smem[4096 + s * 8]);
        }
        __syncthreads();

        bf16x8 ah[4], bh[4];
#pragma unroll
        for (int m = 0; m < 4; ++m) {
            int ra = wr * 64 + m * 16 + fr;
            ah[m] = *(const bf16x8*)&smem[(kc * 128 + ra) * 8];
            int rb = wc * 64 + m * 16 + fr;
            bh[m] = *(const bf16x8*)&smem[4096 + (kc * 128 + rb) * 8];
        }
#pragma unroll
        for (int m = 0; m < 4; ++m)
#pragma unroll
            for (int n = 0; n < 4; ++n)
                acc[m][n] = __builtin_amdgcn_mfma_f32_16x16x32_bf16(ah[m], bh[n], acc[m][n], 0, 0, 0);
        __syncthreads();
    }
    const int crow0 = bm * 128 + wr * 64 + kc * 4;
    const int ccol0 = bn * 128 + wc * 64 + fr;
#pragma unroll
    for (int m = 0; m < 4; ++m)
#pragma unroll
        for (int n = 0; n < 4; ++n)
#pragma unroll
            for (int j = 0; j < 4; ++j)
                g_sims[(size_t)(crow0 + m * 16 + j) * NDB + ccol0 + n * 16] = acc[m][n][j];

    if (mirror) {
#pragma unroll
        for (int m = 0; m < 4; ++m)
#pragma unroll
            for (int n = 0; n < 4; ++n) {
                size_t r = (size_t)(bn * 128 + wc * 64 + n * 16 + fr);
                size_t cix = (size_t)(bm * 128 + wr * 64 + m * 16 + kc * 4);
                *(f32x4*)&g_sims[r * NDB + cix] = acc[m][n];
            }
    }

    float* rowhalf = (float*)smem;
    float* colhalf = (float*)smem + 256;
#pragma unroll
    for (int m = 0; m < 4; ++m)
#pragma unroll
        for (int j = 0; j < 4; ++j) {
            float v = fmaxf(fmaxf(acc[m][0][j], acc[m][1][j]),
                            fmaxf(acc[m][2][j], acc[m][3][j]));
#pragma unroll
            for (int o = 1; o < 16; o <<= 1) v = fmaxf(v, __shfl_xor(v, o));
            if (fr == 0) rowhalf[(wr * 64 + m * 16 + kc * 4 + j) * 2 + wc] = v;
        }
    if (mirror) {
#pragma unroll
        for (int n = 0; n < 4; ++n) {
            float v = acc[0][n][0];
#pragma unroll
            for (int m = 0; m < 4; ++m)
#pragma unroll
                for (int j = 0; j < 4; ++j) v = fmaxf(v, acc[m][n][j]);
            v = fmaxf(v, __shfl_xor(v, 16));
            v = fmaxf(v, __shfl_xor(v, 32));
            if (kc == 0) colhalf[(wc * 64 + n * 16 + fr) * 2 + wr] = v;
        }
    }
    __syncthreads();
    if (t < 128) {
        g_tmax[(size_t)(bm * 128 + t) * NT + bn] = fmaxf(rowhalf[t * 2], rowhalf[t * 2 + 1]);
        if (mirror)
            g_tmax[(size_t)(bn * 128 + t) * NT + bm] = fmaxf(colhalf[t * 2], colhalf[t * 2 + 1]);
    }
}

// ------- 3. select: margin-threshold collect + exact rescore -> g_topk -------
__global__ __launch_bounds__(256) void select_kernel(
        const float* __restrict__ x_real, const float* __restrict__ x_imag,
        const float* __restrict__ att_real, const float* __restrict__ att_imag) {
    __shared__ float stm[96];
    __shared__ unsigned char tlist[96];
    __shared__ unsigned long long cand[1024];
    __shared__ unsigned long long skey[64];
    __shared__ unsigned long long skey2[64];
    __shared__ unsigned long long rkey[64];
    __shared__ int ridx[64];
    __shared__ int s_idx[KTOP];
    __shared__ float qre[FD], qim[FD];
    __shared__ unsigned s_cnt;
    __shared__ int s_ntile, s_S, s_R;
    __shared__ float s_T, s_V32;
    __shared__ unsigned long long s_red[4];
    __shared__ unsigned long long s_last;
    int b = blockIdx.x, t = threadIdx.x;
    int wave = t >> 6, lane = t & 63;

    if (t < 96) stm[t] = g_tmax[(size_t)b * NT + t];
    if (t < 128) *(float4*)&qre[t * 4] = *(const float4*)(x_real + (size_t)b * FD + t * 4);
    else         *(float4*)&qim[(t - 128) * 4] = *(const float4*)(x_imag + (size_t)b * FD + (t - 128) * 4);
    if (t == 0) { s_cnt = 0; s_ntile = 0; s_S = 0; s_R = 0; }
    __syncthreads();

    if (t < 96) {   // T = 32nd-largest tile max (parallel rank)
        float v = stm[t];
        int cnt = 0;
        for (int i = 0; i < 96; ++i) {
            float o = stm[i];
            cnt += (o > v) || (o == v && i < t);
        }
        if (cnt == KTOP - 1) s_T = v;
    }
    __syncthreads();
    const float Tm = s_T - DEL2;

    if (t < 96 && stm[t] >= Tm) { int p = atomicAdd(&s_ntile, 1); tlist[p] = (unsigned char)t; }
    __syncthreads();
    const int ntile = s_ntile;

    const float* rowp = g_sims + (size_t)b * NDB;
    for (int base = 0; base < ntile; base += 8) {
        int ti = base + (t >> 5);
        if (ti < ntile) {
            int tile = tlist[ti];
            int c4 = (t & 31) * 4;
            float4 v = *(const float4*)(rowp + tile * 128 + c4);
            int gidx = tile * 128 + c4;
            if (v.x >= Tm) { unsigned p = atomicAdd(&s_cnt, 1u); if (p < 1024) cand[p] = ((unsigned long long)fkey(__float_as_uint(v.x)) << 32) | (unsigned)(~(gidx + 0)); }
            if (v.y >= Tm) { unsigned p = atomicAdd(&s_cnt, 1u); if (p < 1024) cand[p] = ((unsigned long long)fkey(__float_as_uint(v.y)) << 32) | (unsigned)(~(gidx + 1)); }
            if (v.z >= Tm) { unsigned p = atomicAdd(&s_cnt, 1u); if (p < 1024) cand[p] = ((unsigned long long)fkey(__float_as_uint(v.z)) << 32) | (unsigned)(~(gidx + 2)); }
            if (v.w >= Tm) { unsigned p = atomicAdd(&s_cnt, 1u); if (p < 1024) cand[p] = ((unsigned long long)fkey(__float_as_uint(v.w)) << 32) | (unsigned)(~(gidx + 3)); }
        }
    }
    __syncthreads();
    unsigned cnt_raw = s_cnt;
    int c = (int)cnt_raw; if (c > 1024) c = 1024;

    // sorted top-64 -> skey
    if (c <= 64) {
        if (wave == 0) skey[lane] = bitonic64((lane < c) ? cand[lane] : 0ull, lane);
        __syncthreads();
    } else if (c <= 128) {
        // two-wave sort + one bitonic merge: exact sorted top-64 of <=128
        if (wave < 2) {
            int i = wave * 64 + lane;
            unsigned long long vv = bitonic64((i < c) ? cand[i] : 0ull, lane);
            if (wave == 0) skey[lane] = vv; else skey2[lane] = vv;
        }
        __syncthreads();
        if (wave == 0) {
            unsigned long long a = skey[lane], b2 = skey2[63 - lane];
            unsigned long long vv = a > b2 ? a : b2;   // top-64, bitonic
#pragma unroll
            for (int j = 32; j > 0; j >>= 1) {         // bitonic merge -> descending
                unsigned long long o = __shfl_xor(vv, j);
                bool keepmax = (lane & j) == 0;
                vv = keepmax ? (vv > o ? vv : o) : (vv < o ? vv : o);
            }
            skey[lane] = vv;
        }
        __syncthreads();
    } else {
        unsigned long long last = ~0ull;
        for (int it = 0; it < 64; ++it) {
            unsigned long long m = 0;
            for (int i = t; i < c; i += 256) { unsigned long long k = cand[i]; if (k < last && k > m) m = k; }
#pragma unroll
            for (int o = 32; o > 0; o >>= 1) { unsigned long long x = __shfl_xor(m, o); m = x > m ? x : m; }
            if (lane == 0) s_red[wave] = m;
            __syncthreads();
            if (t == 0) {
                unsigned long long w = s_red[0];
#pragma unroll
                for (int i = 1; i < 4; ++i) w = s_red[i] > w ? s_red[i] : w;
                skey[it] = w; s_last = w;
            }
            __syncthreads();
            last = s_last;
        }
    }
    if (t == 0) s_V32 = unfkey((unsigned)(skey[31] >> 32));
    __syncthreads();
    const float V32 = s_V32;
    bool fallback = (cnt_raw > 1024);
    if (c > 64) {
        float v63 = unfkey((unsigned)(skey[63] >> 32));
        fallback = fallback || (v63 >= V32 - DEL2);
    }
    const float qninv = g_ninv[b];

    if (!fallback) {
        if (wave == 0) {
            unsigned long long k = skey[lane];
            float v = (k != 0) ? unfkey((unsigned)(k >> 32)) : -INFINITY;
            int idx = (int)(~(unsigned)k);
            bool sure = v > V32 + DEL2;
            bool amb  = !sure && v >= V32 - DEL2;
            unsigned long long smask = __ballot(sure);
            int S = __popcll(smask);
            if (sure) s_idx[lane] = idx;
            if (amb)  ridx[lane - S] = idx;
            if (lane == 0) s_S = S;
            unsigned long long amask = __ballot(amb);
            if (lane == 0) s_R = __popcll(amask);
        }
        __syncthreads();
        int S = s_S, R = s_R;
        for (int r = wave; r < R; r += 4) {
            int j = ridx[r];
            const float *dre, *dim_;
            if (j < BQ) { dre = x_real + (size_t)j * FD; dim_ = x_imag + (size_t)j * FD; }
            else        { dre = att_real + (size_t)(j - BQ) * FD; dim_ = att_imag + (size_t)(j - BQ) * FD; }
            float4 a0 = *(const float4*)&qre[lane * 8], a1 = *(const float4*)&qre[lane * 8 + 4];
            float4 b0 = *(const float4*)(dre + lane * 8), b1 = *(const float4*)(dre + lane * 8 + 4);
            float4 c0 = *(const float4*)&qim[lane * 8], c1 = *(const float4*)&qim[lane * 8 + 4];
            float4 d0 = *(const float4*)(dim_ + lane * 8), d1 = *(const float4*)(dim_ + lane * 8 + 4);
            float s = a0.x * b0.x + a0.y * b0.y + a0.z * b0.z + a0.w * b0.w
                    + a1.x * b1.x + a1.y * b1.y + a1.z * b1.z + a1.w * b1.w
                    + c0.x * d0.x + c0.y * d0.y + c0.z * d0.z + c0.w * d0.w
                    + c1.x * d1.x + c1.y * d1.y + c1.z * d1.z + c1.w * d1.w;
#pragma unroll
            for (int o = 32; o > 0; o >>= 1) s += __shfl_xor(s, o);
            float v = s * qninv * g_ninv[j];
            if (lane == 0) rkey[r] = ((unsigned long long)fkey(__float_as_uint(v)) << 32) | (unsigned)(~j);
        }
        __syncthreads();
        if (wave == 0) {
            unsigned long long vv = bitonic64((lane < s_R) ? rkey[lane] : 0ull, lane);
            if (lane < KTOP - S) s_idx[S + lane] = (int)(~(unsigned)vv);
        }
        __syncthreads();
    } else {
        for (int r = wave; r < c; r += 4) {
            int j = (int)(~(unsigned)cand[r]);
            const float *dre, *dim_;
            if (j < BQ) { dre = x_real + (size_t)j * FD; dim_ = x_imag + (size_t)j * FD; }
            else        { dre = att_real + (size_t)(j - BQ) * FD; dim_ = att_imag + (size_t)(j - BQ) * FD; }
            float4 a0 = *(const float4*)&qre[lane * 8], a1 = *(const float4*)&qre[lane * 8 + 4];
            float4 b0 = *(const float4*)(dre + lane * 8), b1 = *(const float4*)(dre + lane * 8 + 4);
            float4 c0 = *(const float4*)&qim[lane * 8], c1 = *(const float4*)&qim[lane * 8 + 4];
            float4 d0 = *(const float4*)(dim_ + lane * 8), d1 = *(const float4*)(dim_ + lane * 8 + 4);
            float s = a0.x * b0.x + a0.y * b0.y + a0.z * b0.z + a0.w * b0.w
                    + a1.x * b1.x + a1.y * b1.y + a1.z * b1.z + a1.w * b1.w
                    + c0.x * d0.x + c0.y * d0.y + c0.z * d0.z + c0.w * d0.w
                    + c1.x * d1.x + c1.y * d1.y + c1.z * d1.z + c1.w * d1.w;
#pragma unroll
            for (int o = 32; o > 0; o >>= 1) s += __shfl_xor(s, o);
            float v = s * qninv * g_ninv[j];
            if (lane == 0) cand[r] = ((unsigned long long)fkey(__float_as_uint(v)) << 32) | (unsigned)(~j);
        }
        __syncthreads();
        unsigned long long last = ~0ull;
        for (int it = 0; it < KTOP; ++it) {
            unsigned long long m = 0;
            for (int i = t; i < c; i += 256) { unsigned long long k = cand[i]; if (k < last && k > m) m = k; }
#pragma unroll
            for (int o = 32; o > 0; o >>= 1) { unsigned long long x = __shfl_xor(m, o); m = x > m ? x : m; }
            if (lane == 0) s_red[wave] = m;
            __syncthreads();
            if (t == 0) {
                unsigned long long w = s_red[0];
#pragma unroll
                for (int i = 1; i < 4; ++i) w = s_red[i] > w ? s_red[i] : w;
                s_idx[it] = (int)(~(unsigned)w); s_last = w;
            }
            __syncthreads();
            last = s_last;
        }
    }
    __syncthreads();
    if (t < KTOP) g_topk[b * KTOP + t] = s_idx[t];
}

// ------- 4. agg: gather 32 neighbors + circular mean + blend -----------------
__global__ __launch_bounds__(256) void agg_kernel(
        const float* __restrict__ x_real, const float* __restrict__ x_imag,
        const float* __restrict__ att_real, const float* __restrict__ att_imag,
        const float* __restrict__ alpha_p, float* __restrict__ out) {
    __shared__ int idxs[KTOP];
    int b = blockIdx.x, t = threadIdx.x;
    if (t < KTOP) idxs[t] = g_topk[b * KTOP + t];
    __syncthreads();
    float a = alpha_p[0];
    a = fminf(fmaxf(a, 0.0f), 1.0f);
    int f = 2 * t;
    float sr0 = 0, sc0 = 0, ss0 = 0, sr1 = 0, sc1 = 0, ss1 = 0;
    for (int k = 0; k < KTOP; ++k) {
        int idx = idxs[k];
        const float *re, *im;
        if (idx < BQ) { re = x_real + (size_t)idx * FD;          im = x_imag + (size_t)idx * FD; }
        else          { re = att_real + (size_t)(idx - BQ) * FD; im = att_imag + (size_t)(idx - BQ) * FD; }
        float2 vr = *(const float2*)(re + f);
        float2 vi = *(const float2*)(im + f);
        float s0 = vr.x * vr.x + vi.x * vi.x;
        if (s0 > 0.0f) {
            float iv = frsq(s0);
            sr0 += s0 * iv; sc0 += vr.x * iv; ss0 += vi.x * iv;
        } else sc0 += 1.0f;                     // atan2(0,0)=0
        float s1 = vr.y * vr.y + vi.y * vi.y;
        if (s1 > 0.0f) {
            float iv = frsq(s1);
            sr1 += s1 * iv; sc1 += vr.y * iv; ss1 += vi.y * iv;
        } else sc1 += 1.0f;
    }
    const float inv = 1.0f / KTOP;
    float mr0 = sr0 * inv + EPSF, mc0 = sc0 * inv, ms0 = ss0 * inv;
    float mr1 = sr1 * inv + EPSF, mc1 = sc1 * inv, ms1 = ss1 * inv;
    float q0 = mc0 * mc0 + ms0 * ms0;
    float q1 = mc1 * mc1 + ms1 * ms1;
    float i0 = (q0 > 0.0f) ? frsq(q0) : 0.0f;
    float i1 = (q1 > 0.0f) ? frsq(q1) : 0.0f;
    float c0v = (q0 > 0.0f) ? mc0 * i0 : 1.0f;
    float s0v = ms0 * i0;
    float c1v = (q1 > 0.0f) ? mc1 * i1 : 1.0f;
    float s1v = ms1 * i1;
    size_t obase = (size_t)b * FD + f;
    float2 xr = *(const float2*)(x_real + obase);
    float2 xi = *(const float2*)(x_imag + obase);
    float2 outr = make_float2((1.0f - a) * xr.x + a * (mr0 * c0v),
                              (1.0f - a) * xr.y + a * (mr1 * c1v));
    float2 outi = make_float2((1.0f - a) * xi.x + a * (mr0 * s0v),
                              (1.0f - a) * xi.y + a * (mr1 * s1v));
    *(float2*)(out + obase) = outr;
    *(float2*)(out + (size_t)BQ * FD + obase) = outi;
}

extern "C" void kernel_launch(void* const* d_in, const int* in_sizes, int n_in,
                              void* d_out, int out_size, void* d_ws, size_t ws_size,
                              hipStream_t stream) {
    const float* x_real   = (const float*)d_in[0];
    const float* x_imag   = (const float*)d_in[1];
    const float* att_real = (const float*)d_in[2];
    const float* att_imag = (const float*)d_in[3];
    const float* alpha    = (const float*)d_in[4];
    float* out = (float*)d_out;

    normalize_kernel<<<NDB / 16, 256, 0, stream>>>(x_real, x_imag, att_real, att_imag);
    gemm_mfma<<<NTILES, 256, 0, stream>>>();
    select_kernel<<<BQ, 256, 0, stream>>>(x_real, x_imag, att_real, att_imag);
    agg_kernel<<<BQ, 256, 0, stream>>>(x_real, x_imag, att_real, att_imag, alpha, out);
}